// Round 12
// baseline (235.668 us; speedup 1.0000x reference)
//
#include <hip/hip_runtime.h>
#include <hip/hip_bf16.h>

#define T_TOK 4096
#define HD    1024
#define FFD   2048
#define NE    8

typedef __attribute__((ext_vector_type(8))) short short8;
typedef __attribute__((ext_vector_type(4))) float f32x4;

__device__ __forceinline__ unsigned short f2bf(float f) {
  __hip_bfloat16 h = __float2bfloat16(f);
  return __builtin_bit_cast(unsigned short, h);
}

__device__ __forceinline__ void gload_lds16(const unsigned short* g, unsigned short* l) {
  __builtin_amdgcn_global_load_lds(
      (const __attribute__((address_space(1))) unsigned int*)g,
      (__attribute__((address_space(3))) unsigned int*)l, 16, 0, 0);
}

// ---------------- fused prep: gate (+zero out, +x->bf16) || W1^T || W2^T ----------
__global__ __launch_bounds__(256) void prep_kernel(
    const float* __restrict__ x, const float* __restrict__ Wg,
    const float* __restrict__ bg,
    const float* __restrict__ W1, const float* __restrict__ W2,
    int* __restrict__ top_i, float2* __restrict__ top_w,
    unsigned short* __restrict__ xbf,
    unsigned short* __restrict__ W1T, unsigned short* __restrict__ W2T,
    float* __restrict__ out)
{
  __shared__ float tile[64][69];
  const int bid = blockIdx.x;
  const int tid = threadIdx.x;

  if (bid < T_TOK / 4) {
    // ---- gate section ----
    {
      size_t b = ((size_t)bid * 256 + tid) * 16;
      float4 z = make_float4(0.f, 0.f, 0.f, 0.f);
#pragma unroll
      for (int q = 0; q < 4; ++q) *(float4*)(out + b + q * 4) = z;
    }
    const int wave = tid >> 6;
    const int lane = tid & 63;
    const int t = bid * 4 + wave;

    float acc[NE];
#pragma unroll
    for (int e = 0; e < NE; ++e) acc[e] = 0.f;

    const float* xr = x + (size_t)t * HD;
    unsigned short* xo = xbf + (size_t)t * HD;
#pragma unroll
    for (int it = 0; it < 4; ++it) {
      const int h0 = lane * 4 + it * 256;
      float4 xv = *(const float4*)(xr + h0);
#pragma unroll
      for (int j = 0; j < 4; ++j) {
        float xs = (&xv.x)[j];
        float4 a = *(const float4*)(Wg + (size_t)(h0 + j) * NE);
        float4 b = *(const float4*)(Wg + (size_t)(h0 + j) * NE + 4);
        acc[0] = fmaf(xs, a.x, acc[0]); acc[1] = fmaf(xs, a.y, acc[1]);
        acc[2] = fmaf(xs, a.z, acc[2]); acc[3] = fmaf(xs, a.w, acc[3]);
        acc[4] = fmaf(xs, b.x, acc[4]); acc[5] = fmaf(xs, b.y, acc[5]);
        acc[6] = fmaf(xs, b.z, acc[6]); acc[7] = fmaf(xs, b.w, acc[7]);
      }
      ushort4 u;
      u.x = f2bf(xv.x); u.y = f2bf(xv.y); u.z = f2bf(xv.z); u.w = f2bf(xv.w);
      *(ushort4*)(xo + h0) = u;
    }
#pragma unroll
    for (int off = 32; off > 0; off >>= 1) {
#pragma unroll
      for (int e = 0; e < NE; ++e) acc[e] += __shfl_xor(acc[e], off);
    }
    if (lane == 0) {
      float lg[NE];
#pragma unroll
      for (int e = 0; e < NE; ++e) lg[e] = acc[e] + bg[e];
      int i1 = 0;
#pragma unroll
      for (int e = 1; e < NE; ++e) if (lg[e] > lg[i1]) i1 = e;
      int i2 = (i1 == 0) ? 1 : 0;
#pragma unroll
      for (int e = 0; e < NE; ++e) if (e != i1 && lg[e] > lg[i2]) i2 = e;
      float p2 = expf(lg[i2] - lg[i1]);
      float s  = 1.f + p2;
      top_i[t] = i1 | (i2 << 8);
      top_w[t] = make_float2(1.f / s, p2 / s);
    }
    return;
  }

  // ---- transpose sections: [E][R][C] fp32 -> [E][C][R] bf16 ----
  const float* in; unsigned short* ow; int R, C, idx;
  if (bid < T_TOK / 4 + 4096) {
    idx = bid - T_TOK / 4;          in = W1; ow = W1T; R = HD;  C = FFD;
  } else {
    idx = bid - (T_TOK / 4 + 4096); in = W2; ow = W2T; R = FFD; C = HD;
  }
  const int cpt = C >> 6, rpt = R >> 6;
  const int cx = idx % cpt;
  const int cy = (idx / cpt) % rpt;
  const int z  = idx / (cpt * rpt);
  const int r0 = cy * 64, c0 = cx * 64;

  const float* ip = in + ((size_t)z * R + r0) * C + c0;
  int tr = tid >> 4, tc = (tid & 15) * 4;
#pragma unroll
  for (int j = 0; j < 4; ++j) {
    float4 v = *(const float4*)(ip + (size_t)(tr + j * 16) * C + tc);
    float* tp = &tile[tr + j * 16][tc];
    tp[0] = v.x; tp[1] = v.y; tp[2] = v.z; tp[3] = v.w;
  }
  __syncthreads();
  unsigned short* op = ow + ((size_t)z * C + c0) * R + r0;
  int oc = tid >> 4, orr = (tid & 15) * 4;
#pragma unroll
  for (int j = 0; j < 4; ++j) {
    int c = oc + j * 16;
    ushort4 w;
    w.x = f2bf(tile[orr + 0][c]);
    w.y = f2bf(tile[orr + 1][c]);
    w.z = f2bf(tile[orr + 2][c]);
    w.w = f2bf(tile[orr + 3][c]);
    *(ushort4*)(op + (size_t)c * R + orr) = w;
  }
}

// ---------------- route: per-expert compaction via prefix scan (deterministic) ----
__global__ __launch_bounds__(256) void route_kernel(
    const int* __restrict__ top_i, const float2* __restrict__ top_w,
    int* __restrict__ counts, int* __restrict__ ids, float* __restrict__ wts)
{
  const int e   = blockIdx.x;
  const int tid = threadIdx.x;
  __shared__ int psum[256];

  const int t0 = tid * 16;
  unsigned int flags = 0;
  int cnt = 0;
#pragma unroll
  for (int j = 0; j < 16; ++j) {
    int ti = top_i[t0 + j];
    bool m = ((ti & 255) == e) || (((ti >> 8) & 255) == e);
    flags |= (m ? 1u : 0u) << j;
    cnt += m;
  }
  psum[tid] = cnt;
  __syncthreads();
  for (int off = 1; off < 256; off <<= 1) {
    int v = (tid >= off) ? psum[tid - off] : 0;
    __syncthreads();
    psum[tid] += v;
    __syncthreads();
  }
  int rank = psum[tid] - cnt;
#pragma unroll
  for (int j = 0; j < 16; ++j) {
    if (flags & (1u << j)) {
      int t = t0 + j;
      int ti = top_i[t];
      float2 w = top_w[t];
      ids[e * T_TOK + rank] = t;
      wts[e * T_TOK + rank] = ((ti & 255) == e) ? w.x : w.y;
      ++rank;
    }
  }
  if (tid == 255) counts[e] = psum[255];
}

// ---------------- grouped pair-GEMM: 256x128 dbuf, single-barrier 2-phase ---------
// T3-minimum loop (m230/m248-proven at this family):
//   stage(t+1) -> ds_read+MFMA(t) -> lgkmcnt(0)+vmcnt(0) -> ONE barrier
// vmcnt(0) lands AFTER the compute phase, so next-tile loads hide under MFMA.
// Barrier proof: crossing it => all waves read buf[cur] (lgkmcnt0 before it) AND
// all waves' DMA into buf[cur^1] landed (vmcnt0) -> next iter may overwrite cur.
// 8 waves (4M x 2N), wave tile 64x64 (same frag math as r9). 96KB LDS, 1 blk/CU.
// e = bid&7 pins expert to XCD (FETCH ~ideal, r9). XOR swizzle: 0 conflicts.
// KSPLIT via f32 atomics (G2); bias at kp==0. Grid over-provisioned, early-exit.
template<int KD, int ND, int KSPLIT, bool G1M, bool GATHER_A>
__global__ __launch_bounds__(512, 2) void pair_gemm256_kernel(
    const unsigned short* __restrict__ A,
    const unsigned short* __restrict__ BT,
    const float* __restrict__ bias,
    const int* __restrict__ counts, const int* __restrict__ ids,
    const float* __restrict__ wts,
    unsigned short* __restrict__ Hout, float* __restrict__ out)
{
  constexpr int CT    = ND / 128;
  constexpr int KTILE = KD / KSPLIT;
  constexpr int NT    = KTILE / 64;

  const int e    = blockIdx.x & 7;
  const int slot = blockIdx.x >> 3;
  int cnt = 0, base = 0;
#pragma unroll
  for (int k = 0; k < NE; ++k) {
    int c = counts[k];
    if (k < e)  base += (c + 255) & ~255;
    if (k == e) cnt = c;
  }
  const int ntiles = (cnt + 255) >> 8;
  if (slot >= ntiles * CT * KSPLIT) return;
  const int rt   = slot % ntiles;            // fastest -> B tile hot in L2
  const int ct   = (slot / ntiles) % CT;
  const int kp   = slot / (ntiles * CT);
  const int row0 = base + rt * 256;
  const int koff = kp * KTILE;

  __shared__ __align__(16) unsigned short As[2][256 * 64];  // 64 KB
  __shared__ __align__(16) unsigned short Bs[2][128 * 64];  // 32 KB

  const int tid  = threadIdx.x;
  const int w    = tid >> 6;      // 0..7
  const int lane = tid & 63;
  const int g    = lane >> 4;     // k-group 0..3
  const int rA   = lane & 15;
  const int wr   = w >> 1;        // wave M index 0..3
  const int wc   = w & 1;         // wave N index 0..1
  const int sw   = rA & 7;        // read-side swizzle key
  const int srow = lane >> 3;                 // staging row in 8-row group
  const int lc8  = ((lane & 7) ^ srow) * 8;   // pre-swizzled source chunk

  // per-thread A-row source pointers (4 groups of 8 rows per wave = 32 rows, x8 = 256)
  const unsigned short* arow[4];
#pragma unroll
  for (int jj = 0; jj < 4; ++jj) {
    const int lrow = w * 32 + jj * 8 + srow;
    int src;
    if constexpr (GATHER_A) {
      int i = rt * 256 + lrow;
      src = ids[e * T_TOK + (i < cnt ? i : cnt - 1)];
    } else {
      src = row0 + lrow;
    }
    arow[jj] = A + (size_t)src * KD + koff + lc8;
  }
  // B rows: 2 groups of 8 per wave = 16, x8 = 128
  const unsigned short* brow[2];
#pragma unroll
  for (int jj = 0; jj < 2; ++jj) {
    const int lrow = w * 16 + jj * 8 + srow;
    brow[jj] = BT + ((size_t)e * ND + ct * 128 + lrow) * KD + koff + lc8;
  }

  f32x4 acc[4][4];
#pragma unroll
  for (int mf = 0; mf < 4; ++mf)
#pragma unroll
    for (int nf = 0; nf < 4; ++nf)
      acc[mf][nf] = (f32x4){0.f, 0.f, 0.f, 0.f};

  auto stage = [&](int buf, int kc) {
#pragma unroll
    for (int jj = 0; jj < 4; ++jj)
      gload_lds16(arow[jj] + kc, &As[buf][(w * 32 + jj * 8) * 64]);
#pragma unroll
    for (int jj = 0; jj < 2; ++jj)
      gload_lds16(brow[jj] + kc, &Bs[buf][(w * 16 + jj * 8) * 64]);
  };

  stage(0, 0);
  asm volatile("s_waitcnt vmcnt(0)" ::: "memory");
  __builtin_amdgcn_s_barrier();

#pragma unroll 2
  for (int t = 0; t < NT; ++t) {
    const int cur = t & 1;
    if (t + 1 < NT) stage(cur ^ 1, (t + 1) * 64);   // in flight across compute
    __builtin_amdgcn_sched_barrier(0);

#pragma unroll
    for (int ks = 0; ks < 2; ++ks) {
      const int pc = ((ks * 4 + g) ^ sw) << 3;
      short8 bf[4];
#pragma unroll
      for (int nf = 0; nf < 4; ++nf)
        bf[nf] = *(const short8*)&Bs[cur][(wc * 64 + nf * 16 + rA) * 64 + pc];
#pragma unroll
      for (int mf = 0; mf < 4; ++mf) {
        short8 af = *(const short8*)&As[cur][(wr * 64 + mf * 16 + rA) * 64 + pc];
#pragma unroll
        for (int nf = 0; nf < 4; ++nf)
          acc[mf][nf] = __builtin_amdgcn_mfma_f32_16x16x32_bf16(
              af, bf[nf], acc[mf][nf], 0, 0, 0);
      }
    }

    asm volatile("s_waitcnt lgkmcnt(0) vmcnt(0)" ::: "memory"); // reads done + t+1 landed
    __builtin_amdgcn_sched_barrier(0);
    __builtin_amdgcn_s_barrier();                  // single barrier per K-step
    __builtin_amdgcn_sched_barrier(0);
  }

  // ---- epilogue ----
  float bv[4];
#pragma unroll
  for (int nf = 0; nf < 4; ++nf)
    bv[nf] = (KSPLIT == 1 || kp == 0)
                 ? bias[e * ND + ct * 128 + wc * 64 + nf * 16 + rA] : 0.f;

  if constexpr (G1M) {
#pragma unroll
    for (int mf = 0; mf < 4; ++mf)
#pragma unroll
      for (int r = 0; r < 4; ++r) {
        const int row = row0 + wr * 64 + mf * 16 + g * 4 + r;
        unsigned short* hrow = Hout + (size_t)row * FFD + ct * 128 + wc * 64 + rA;
#pragma unroll
        for (int nf = 0; nf < 4; ++nf)
          hrow[nf * 16] = f2bf(fmaxf(acc[mf][nf][r] + bv[nf], 0.f));
      }
  } else {
#pragma unroll
    for (int mf = 0; mf < 4; ++mf)
#pragma unroll
      for (int r = 0; r < 4; ++r) {
        const int i = rt * 256 + wr * 64 + mf * 16 + g * 4 + r;
        if (i >= cnt) continue;
        const int tok = ids[e * T_TOK + i];
        const float wt = wts[e * T_TOK + i];
        float* orow = out + (size_t)tok * HD + ct * 128 + wc * 64 + rA;
#pragma unroll
        for (int nf = 0; nf < 4; ++nf)
          atomicAdd(&orow[nf * 16], wt * (acc[mf][nf][r] + bv[nf]));
      }
  }
}

extern "C" void kernel_launch(void* const* d_in, const int* in_sizes, int n_in,
                              void* d_out, int out_size, void* d_ws, size_t ws_size,
                              hipStream_t stream) {
  const float* x  = (const float*)d_in[0];
  const float* Wg = (const float*)d_in[1];
  const float* bg = (const float*)d_in[2];
  const float* W1 = (const float*)d_in[3];
  const float* b1 = (const float*)d_in[4];
  const float* W2 = (const float*)d_in[5];
  const float* b2 = (const float*)d_in[6];
  float* out = (float*)d_out;

  // ws: [counts 512B][top_i 16K][top_w 32K][ids 128K][wts 128K]
  //     [xbf 8MB][W1T 32MB][W2T 32MB][H 40MB]  ~= 112.8 MB (<= 118.3 proven)
  const size_t OFF_TOPI = 512;
  const size_t OFF_TOPW = OFF_TOPI + (size_t)T_TOK * 4;
  const size_t OFF_IDS  = OFF_TOPW + (size_t)T_TOK * 8;
  const size_t OFF_WTS  = OFF_IDS + (size_t)T_TOK * NE * 4;
  const size_t OFF_XBF  = OFF_WTS + (size_t)T_TOK * NE * 4;
  const size_t OFF_W1T  = OFF_XBF + (size_t)T_TOK * HD * 2;
  const size_t OFF_W2T  = OFF_W1T + (size_t)NE * HD * FFD * 2;
  const size_t OFF_H    = OFF_W2T + (size_t)NE * HD * FFD * 2;
  const size_t REQ      = OFF_H + (size_t)10240 * FFD * 2;

  if (ws_size < REQ) return;

  int*            counts = (int*)d_ws;
  int*            top_i  = (int*)((char*)d_ws + OFF_TOPI);
  float2*         top_w  = (float2*)((char*)d_ws + OFF_TOPW);
  int*            ids    = (int*)((char*)d_ws + OFF_IDS);
  float*          wts    = (float*)((char*)d_ws + OFF_WTS);
  unsigned short* xbf    = (unsigned short*)((char*)d_ws + OFF_XBF);
  unsigned short* W1T    = (unsigned short*)((char*)d_ws + OFF_W1T);
  unsigned short* W2T    = (unsigned short*)((char*)d_ws + OFF_W2T);
  unsigned short* H      = (unsigned short*)((char*)d_ws + OFF_H);

  // fused prep: gate (1024) + W1T (4096) + W2T (4096)
  prep_kernel<<<T_TOK / 4 + 2 * 4096, 256, 0, stream>>>(
      x, Wg, bg, W1, W2, top_i, top_w, xbf, W1T, W2T, out);
  route_kernel<<<NE, 256, 0, stream>>>(top_i, top_w, counts, ids, wts);

  // G1: 256x128 tiles; typical jobs/expert = ntiles(4-5) x 16 = 64-80; over-provision
  pair_gemm256_kernel<HD, FFD, 1, true, true>
      <<<NE * 256, 512, 0, stream>>>(xbf, W1T, b1, counts, ids, wts, H, nullptr);
  // G2: split-K=2 -> jobs = ntiles(4-5) x 8 x 2 = 64-80
  pair_gemm256_kernel<FFD, HD, 2, false, false>
      <<<NE * 256, 512, 0, stream>>>(H, W2T, b2, counts, ids, wts, nullptr, out);
}

// Round 13
// 171.228 us; speedup vs baseline: 1.3763x; 1.3763x over previous
//
#include <hip/hip_runtime.h>
#include <hip/hip_bf16.h>

#define T_TOK 4096
#define HD    1024
#define FFD   2048
#define NE    8

typedef __attribute__((ext_vector_type(8))) short short8;
typedef __attribute__((ext_vector_type(4))) float f32x4;

__device__ __forceinline__ unsigned short f2bf(float f) {
  __hip_bfloat16 h = __float2bfloat16(f);
  return __builtin_bit_cast(unsigned short, h);
}

__device__ __forceinline__ void gload_lds16(const unsigned short* g, unsigned short* l) {
  __builtin_amdgcn_global_load_lds(
      (const __attribute__((address_space(1))) unsigned int*)g,
      (__attribute__((address_space(3))) unsigned int*)l, 16, 0, 0);
}

// ---------------- fused prep: gate (+zero out, +x->bf16) || W1^T || W2^T ----------
// Sections by blockIdx: [0,1024) gate, [1024,5120) W1 transpose, [5120,9216) W2.
// All independent, all BW-bound -> one launch, no inter-kernel gaps.
__global__ __launch_bounds__(256) void prep_kernel(
    const float* __restrict__ x, const float* __restrict__ Wg,
    const float* __restrict__ bg,
    const float* __restrict__ W1, const float* __restrict__ W2,
    int* __restrict__ top_i, float2* __restrict__ top_w,
    unsigned short* __restrict__ xbf,
    unsigned short* __restrict__ W1T, unsigned short* __restrict__ W2T,
    float* __restrict__ out)
{
  __shared__ float tile[64][69];
  const int bid = blockIdx.x;
  const int tid = threadIdx.x;

  if (bid < T_TOK / 4) {
    // ---- gate section ----
    {
      size_t b = ((size_t)bid * 256 + tid) * 16;
      float4 z = make_float4(0.f, 0.f, 0.f, 0.f);
#pragma unroll
      for (int q = 0; q < 4; ++q) *(float4*)(out + b + q * 4) = z;
    }
    const int wave = tid >> 6;
    const int lane = tid & 63;
    const int t = bid * 4 + wave;

    float acc[NE];
#pragma unroll
    for (int e = 0; e < NE; ++e) acc[e] = 0.f;

    const float* xr = x + (size_t)t * HD;
    unsigned short* xo = xbf + (size_t)t * HD;
#pragma unroll
    for (int it = 0; it < 4; ++it) {
      const int h0 = lane * 4 + it * 256;
      float4 xv = *(const float4*)(xr + h0);
#pragma unroll
      for (int j = 0; j < 4; ++j) {
        float xs = (&xv.x)[j];
        float4 a = *(const float4*)(Wg + (size_t)(h0 + j) * NE);
        float4 b = *(const float4*)(Wg + (size_t)(h0 + j) * NE + 4);
        acc[0] = fmaf(xs, a.x, acc[0]); acc[1] = fmaf(xs, a.y, acc[1]);
        acc[2] = fmaf(xs, a.z, acc[2]); acc[3] = fmaf(xs, a.w, acc[3]);
        acc[4] = fmaf(xs, b.x, acc[4]); acc[5] = fmaf(xs, b.y, acc[5]);
        acc[6] = fmaf(xs, b.z, acc[6]); acc[7] = fmaf(xs, b.w, acc[7]);
      }
      ushort4 u;
      u.x = f2bf(xv.x); u.y = f2bf(xv.y); u.z = f2bf(xv.z); u.w = f2bf(xv.w);
      *(ushort4*)(xo + h0) = u;
    }
#pragma unroll
    for (int off = 32; off > 0; off >>= 1) {
#pragma unroll
      for (int e = 0; e < NE; ++e) acc[e] += __shfl_xor(acc[e], off);
    }
    if (lane == 0) {
      float lg[NE];
#pragma unroll
      for (int e = 0; e < NE; ++e) lg[e] = acc[e] + bg[e];
      int i1 = 0;
#pragma unroll
      for (int e = 1; e < NE; ++e) if (lg[e] > lg[i1]) i1 = e;
      int i2 = (i1 == 0) ? 1 : 0;
#pragma unroll
      for (int e = 0; e < NE; ++e) if (e != i1 && lg[e] > lg[i2]) i2 = e;
      float p2 = expf(lg[i2] - lg[i1]);
      float s  = 1.f + p2;
      top_i[t] = i1 | (i2 << 8);
      top_w[t] = make_float2(1.f / s, p2 / s);
    }
    return;
  }

  // ---- transpose sections: [E][R][C] fp32 -> [E][C][R] bf16 ----
  const float* in; unsigned short* ow; int R, C, idx;
  if (bid < T_TOK / 4 + 4096) {
    idx = bid - T_TOK / 4;          in = W1; ow = W1T; R = HD;  C = FFD;
  } else {
    idx = bid - (T_TOK / 4 + 4096); in = W2; ow = W2T; R = FFD; C = HD;
  }
  const int cpt = C >> 6, rpt = R >> 6;
  const int cx = idx % cpt;
  const int cy = (idx / cpt) % rpt;
  const int z  = idx / (cpt * rpt);
  const int r0 = cy * 64, c0 = cx * 64;

  const float* ip = in + ((size_t)z * R + r0) * C + c0;
  int tr = tid >> 4, tc = (tid & 15) * 4;
#pragma unroll
  for (int j = 0; j < 4; ++j) {
    float4 v = *(const float4*)(ip + (size_t)(tr + j * 16) * C + tc);
    float* tp = &tile[tr + j * 16][tc];
    tp[0] = v.x; tp[1] = v.y; tp[2] = v.z; tp[3] = v.w;
  }
  __syncthreads();
  unsigned short* op = ow + ((size_t)z * C + c0) * R + r0;
  int oc = tid >> 4, orr = (tid & 15) * 4;
#pragma unroll
  for (int j = 0; j < 4; ++j) {
    int c = oc + j * 16;
    ushort4 w;
    w.x = f2bf(tile[orr + 0][c]);
    w.y = f2bf(tile[orr + 1][c]);
    w.z = f2bf(tile[orr + 2][c]);
    w.w = f2bf(tile[orr + 3][c]);
    *(ushort4*)(op + (size_t)c * R + orr) = w;
  }
}

// ---------------- route: per-expert compaction via prefix scan (deterministic) ----
__global__ __launch_bounds__(256) void route_kernel(
    const int* __restrict__ top_i, const float2* __restrict__ top_w,
    int* __restrict__ counts, int* __restrict__ ids, float* __restrict__ wts)
{
  const int e   = blockIdx.x;
  const int tid = threadIdx.x;
  __shared__ int psum[256];

  const int t0 = tid * 16;
  unsigned int flags = 0;
  int cnt = 0;
#pragma unroll
  for (int j = 0; j < 16; ++j) {
    int ti = top_i[t0 + j];
    bool m = ((ti & 255) == e) || (((ti >> 8) & 255) == e);
    flags |= (m ? 1u : 0u) << j;
    cnt += m;
  }
  psum[tid] = cnt;
  __syncthreads();
  for (int off = 1; off < 256; off <<= 1) {
    int v = (tid >= off) ? psum[tid - off] : 0;
    __syncthreads();
    psum[tid] += v;
    __syncthreads();
  }
  int rank = psum[tid] - cnt;
#pragma unroll
  for (int j = 0; j < 16; ++j) {
    if (flags & (1u << j)) {
      int t = t0 + j;
      int ti = top_i[t];
      float2 w = top_w[t];
      ids[e * T_TOK + rank] = t;
      wts[e * T_TOK + rank] = ((ti & 255) == e) ? w.x : w.y;
      ++rank;
    }
  }
  if (tid == 255) counts[e] = psum[255];
}

// ---------------- grouped pair-GEMM: r9 structure VERBATIM -----------------------
// 128^2 tile, 4 waves, single-buffered 32KB LDS, 2 barriers/K-step, 4-5 blk/CU.
// Session evidence: this beats every dbuf/pipelined variant (r8/r10/r12) because
// cross-block TLP is the latency-hiding mechanism and LDS-for-pipelining kills it.
// e = bid&7 pins expert to XCD (FETCH ~ideal). XOR swizzle: 0 conflicts (r5-r12).
// Grid over-provisioned; dead blocks exit instantly (beats persistence, r11).
template<int KD, int ND, bool G1M, bool GATHER_A>
__global__ __launch_bounds__(256, 4) void pair_gemm128_kernel(
    const unsigned short* __restrict__ A,
    const unsigned short* __restrict__ BT,
    const float* __restrict__ bias,
    const int* __restrict__ counts, const int* __restrict__ ids,
    const float* __restrict__ wts,
    unsigned short* __restrict__ Hout, float* __restrict__ out)
{
  constexpr int CT = ND / 128;

  const int e    = blockIdx.x & 7;
  const int slot = blockIdx.x >> 3;
  int cnt = 0, base = 0;
#pragma unroll
  for (int k = 0; k < NE; ++k) {
    int c = counts[k];
    if (k < e)  base += (c + 255) & ~255;
    if (k == e) cnt = c;
  }
  const int ntiles = (cnt + 127) >> 7;
  if (slot >= ntiles * CT) return;
  const int rt   = slot % ntiles;   // fastest -> B tile hot in this XCD's L2
  const int ct   = slot / ntiles;
  const int row0 = base + rt * 128;

  __shared__ __align__(16) unsigned short As[128 * 64];
  __shared__ __align__(16) unsigned short Bs[128 * 64];

  const int tid  = threadIdx.x;
  const int w    = tid >> 6;
  const int lane = tid & 63;
  const int g    = lane >> 4;     // k-group 0..3
  const int rA   = lane & 15;     // row/col within fragment
  const int wr   = w >> 1;        // wave quadrant row 0..1
  const int wc   = w & 1;         // wave quadrant col 0..1
  const int sw   = rA & 7;        // read-side swizzle key
  const int srow = lane >> 3;                 // staging row in 8-row group
  const int lc8  = ((lane & 7) ^ srow) * 8;   // pre-swizzled source chunk

  const unsigned short* arow[4];
#pragma unroll
  for (int jj = 0; jj < 4; ++jj) {
    const int lrow = w * 32 + jj * 8 + srow;
    int src;
    if constexpr (GATHER_A) {
      int i = rt * 128 + lrow;
      src = ids[e * T_TOK + (i < cnt ? i : cnt - 1)];
    } else {
      src = row0 + lrow;
    }
    arow[jj] = A + (size_t)src * KD + lc8;
  }
  const unsigned short* Bb = BT + ((size_t)e * ND + (size_t)ct * 128) * KD + lc8;

  f32x4 acc[4][4];
#pragma unroll
  for (int mf = 0; mf < 4; ++mf)
#pragma unroll
    for (int nf = 0; nf < 4; ++nf)
      acc[mf][nf] = (f32x4){0.f, 0.f, 0.f, 0.f};

  for (int kc = 0; kc < KD; kc += 64) {
    __syncthreads();   // all waves done reading As/Bs
#pragma unroll
    for (int jj = 0; jj < 4; ++jj) {
      const int rg = w * 32 + jj * 8;
      gload_lds16(arow[jj] + kc, &As[rg * 64]);
      gload_lds16(Bb + (size_t)(rg + srow) * KD + kc, &Bs[rg * 64]);
    }
    __syncthreads();   // drain; 4-5 blk/CU cross-block TLP hides it (m97 mechanism)
#pragma unroll
    for (int ks = 0; ks < 2; ++ks) {
      const int pc = ((ks * 4 + g) ^ sw) << 3;
      short8 af[4], bf[4];
#pragma unroll
      for (int mf = 0; mf < 4; ++mf)
        af[mf] = *(const short8*)&As[(wr * 64 + mf * 16 + rA) * 64 + pc];
#pragma unroll
      for (int nf = 0; nf < 4; ++nf)
        bf[nf] = *(const short8*)&Bs[(wc * 64 + nf * 16 + rA) * 64 + pc];
#pragma unroll
      for (int mf = 0; mf < 4; ++mf)
#pragma unroll
        for (int nf = 0; nf < 4; ++nf)
          acc[mf][nf] = __builtin_amdgcn_mfma_f32_16x16x32_bf16(
              af[mf], bf[nf], acc[mf][nf], 0, 0, 0);
    }
  }

  // ---- epilogue ----
  float bv[4];
#pragma unroll
  for (int nf = 0; nf < 4; ++nf)
    bv[nf] = bias[e * ND + ct * 128 + wc * 64 + nf * 16 + rA];

  if constexpr (G1M) {
#pragma unroll
    for (int mf = 0; mf < 4; ++mf)
#pragma unroll
      for (int r = 0; r < 4; ++r) {
        const int row = row0 + wr * 64 + mf * 16 + g * 4 + r;
        unsigned short* hrow = Hout + (size_t)row * FFD + ct * 128 + wc * 64 + rA;
#pragma unroll
        for (int nf = 0; nf < 4; ++nf)
          hrow[nf * 16] = f2bf(fmaxf(acc[mf][nf][r] + bv[nf], 0.f));
      }
  } else {
#pragma unroll
    for (int mf = 0; mf < 4; ++mf)
#pragma unroll
      for (int r = 0; r < 4; ++r) {
        const int i = rt * 128 + wr * 64 + mf * 16 + g * 4 + r;
        if (i >= cnt) continue;
        const int tok = ids[e * T_TOK + i];
        const float wt = wts[e * T_TOK + i];
        float* orow = out + (size_t)tok * HD + ct * 128 + wc * 64 + rA;
#pragma unroll
        for (int nf = 0; nf < 4; ++nf)
          atomicAdd(&orow[nf * 16], wt * (acc[mf][nf][r] + bv[nf]));
      }
  }
}

extern "C" void kernel_launch(void* const* d_in, const int* in_sizes, int n_in,
                              void* d_out, int out_size, void* d_ws, size_t ws_size,
                              hipStream_t stream) {
  const float* x  = (const float*)d_in[0];
  const float* Wg = (const float*)d_in[1];
  const float* bg = (const float*)d_in[2];
  const float* W1 = (const float*)d_in[3];
  const float* b1 = (const float*)d_in[4];
  const float* W2 = (const float*)d_in[5];
  const float* b2 = (const float*)d_in[6];
  float* out = (float*)d_out;

  // ws: [counts 512B][top_i 16K][top_w 32K][ids 128K][wts 128K]
  //     [xbf 8MB][W1T 32MB][W2T 32MB][H 40MB]  ~= 112.8 MB (<= 118.3 proven)
  const size_t OFF_TOPI = 512;
  const size_t OFF_TOPW = OFF_TOPI + (size_t)T_TOK * 4;
  const size_t OFF_IDS  = OFF_TOPW + (size_t)T_TOK * 8;
  const size_t OFF_WTS  = OFF_IDS + (size_t)T_TOK * NE * 4;
  const size_t OFF_XBF  = OFF_WTS + (size_t)T_TOK * NE * 4;
  const size_t OFF_W1T  = OFF_XBF + (size_t)T_TOK * HD * 2;
  const size_t OFF_W2T  = OFF_W1T + (size_t)NE * HD * FFD * 2;
  const size_t OFF_H    = OFF_W2T + (size_t)NE * HD * FFD * 2;
  const size_t REQ      = OFF_H + (size_t)10240 * FFD * 2;

  if (ws_size < REQ) return;

  int*            counts = (int*)d_ws;
  int*            top_i  = (int*)((char*)d_ws + OFF_TOPI);
  float2*         top_w  = (float2*)((char*)d_ws + OFF_TOPW);
  int*            ids    = (int*)((char*)d_ws + OFF_IDS);
  float*          wts    = (float*)((char*)d_ws + OFF_WTS);
  unsigned short* xbf    = (unsigned short*)((char*)d_ws + OFF_XBF);
  unsigned short* W1T    = (unsigned short*)((char*)d_ws + OFF_W1T);
  unsigned short* W2T    = (unsigned short*)((char*)d_ws + OFF_W2T);
  unsigned short* H      = (unsigned short*)((char*)d_ws + OFF_H);

  // fused prep: gate (1024) + W1T (4096) + W2T (4096)
  prep_kernel<<<T_TOK / 4 + 2 * 4096, 256, 0, stream>>>(
      x, Wg, bg, W1, W2, top_i, top_w, xbf, W1T, W2T, out);
  route_kernel<<<NE, 256, 0, stream>>>(top_i, top_w, counts, ids, wts);

  // G1: over-provisioned (worst case ntiles=32, CT=16), dead blocks exit instantly
  pair_gemm128_kernel<HD, FFD, true, true>
      <<<NE * 512, 256, 0, stream>>>(xbf, W1T, b1, counts, ids, wts, H, nullptr);
  // G2: worst case ntiles=32, CT=8
  pair_gemm128_kernel<FFD, HD, false, false>
      <<<NE * 256, 256, 0, stream>>>(H, W2T, b2, counts, ids, wts, nullptr, out);
}

// Round 14
// 169.860 us; speedup vs baseline: 1.3874x; 1.0081x over previous
//
#include <hip/hip_runtime.h>
#include <hip/hip_bf16.h>

#define T_TOK 4096
#define HD    1024
#define FFD   2048
#define NE    8

typedef __attribute__((ext_vector_type(8))) short short8;
typedef __attribute__((ext_vector_type(4))) float f32x4;

__device__ __forceinline__ unsigned short f2bf(float f) {
  __hip_bfloat16 h = __float2bfloat16(f);
  return __builtin_bit_cast(unsigned short, h);
}

__device__ __forceinline__ void gload_lds16(const unsigned short* g, unsigned short* l) {
  __builtin_amdgcn_global_load_lds(
      (const __attribute__((address_space(1))) unsigned int*)g,
      (__attribute__((address_space(3))) unsigned int*)l, 16, 0, 0);
}

// ---------------- fused prep (512 thr): gate || W1^T || W2^T ----------------------
// Sections by blockIdx: [0,512) gate (8 tok/block), [512,2560) W1T, [2560,4608) W2T.
// Transpose: 128(k) x 64(n) tiles, bf16-in-LDS, vector LDS ops, 256B write segments.
// LDS tile: flat [64 n][128 k] ushort, 8B-chunk XOR swizzle key = 2*(n&15)
//   (even key preserves 16B pairing -> phase-2 ds_read_b128 stays aligned).
// Phase-1 write banks: key bits 3-4 disjoint from rg bits 0-1 -> 32 banks, 4-cyc
//   b64 floor. Phase-2 read: 4m' quads, 2-way -> 8-cyc b128 floor.
__global__ __launch_bounds__(512) void prep_kernel(
    const float* __restrict__ x, const float* __restrict__ Wg,
    const float* __restrict__ bg,
    const float* __restrict__ W1, const float* __restrict__ W2,
    int* __restrict__ top_i, float2* __restrict__ top_w,
    unsigned short* __restrict__ xbf,
    unsigned short* __restrict__ W1T, unsigned short* __restrict__ W2T,
    float* __restrict__ out)
{
  __shared__ unsigned short tt[64 * 128];   // 16 KB
  const int bid = blockIdx.x;
  const int tid = threadIdx.x;

  if (bid < T_TOK / 8) {
    // ---- gate section: 8 waves, one token each; also zero out + x->bf16 ----
    {
      size_t b = ((size_t)bid * 512 + tid) * 16;
      float4 z = make_float4(0.f, 0.f, 0.f, 0.f);
#pragma unroll
      for (int q = 0; q < 4; ++q) *(float4*)(out + b + q * 4) = z;
    }
    const int wave = tid >> 6;
    const int lane = tid & 63;
    const int t = bid * 8 + wave;

    float acc[NE];
#pragma unroll
    for (int e = 0; e < NE; ++e) acc[e] = 0.f;

    const float* xr = x + (size_t)t * HD;
    unsigned short* xo = xbf + (size_t)t * HD;
#pragma unroll
    for (int it = 0; it < 4; ++it) {
      const int h0 = lane * 4 + it * 256;
      float4 xv = *(const float4*)(xr + h0);
#pragma unroll
      for (int j = 0; j < 4; ++j) {
        float xs = (&xv.x)[j];
        float4 a = *(const float4*)(Wg + (size_t)(h0 + j) * NE);
        float4 b = *(const float4*)(Wg + (size_t)(h0 + j) * NE + 4);
        acc[0] = fmaf(xs, a.x, acc[0]); acc[1] = fmaf(xs, a.y, acc[1]);
        acc[2] = fmaf(xs, a.z, acc[2]); acc[3] = fmaf(xs, a.w, acc[3]);
        acc[4] = fmaf(xs, b.x, acc[4]); acc[5] = fmaf(xs, b.y, acc[5]);
        acc[6] = fmaf(xs, b.z, acc[6]); acc[7] = fmaf(xs, b.w, acc[7]);
      }
      ushort4 u;
      u.x = f2bf(xv.x); u.y = f2bf(xv.y); u.z = f2bf(xv.z); u.w = f2bf(xv.w);
      *(ushort4*)(xo + h0) = u;
    }
#pragma unroll
    for (int off = 32; off > 0; off >>= 1) {
#pragma unroll
      for (int e = 0; e < NE; ++e) acc[e] += __shfl_xor(acc[e], off);
    }
    if (lane == 0) {
      float lg[NE];
#pragma unroll
      for (int e = 0; e < NE; ++e) lg[e] = acc[e] + bg[e];
      int i1 = 0;
#pragma unroll
      for (int e = 1; e < NE; ++e) if (lg[e] > lg[i1]) i1 = e;
      int i2 = (i1 == 0) ? 1 : 0;
#pragma unroll
      for (int e = 0; e < NE; ++e) if (e != i1 && lg[e] > lg[i2]) i2 = e;
      float p2 = expf(lg[i2] - lg[i1]);
      float s  = 1.f + p2;
      top_i[t] = i1 | (i2 << 8);
      top_w[t] = make_float2(1.f / s, p2 / s);
    }
    return;
  }

  // ---- transpose sections: [E][R][C] fp32 -> [E][C][R] bf16, 128x64 tiles ----
  const float* in; unsigned short* ow; int R, C, idx;
  if (bid < T_TOK / 8 + 2048) {
    idx = bid - T_TOK / 8;          in = W1; ow = W1T; R = HD;  C = FFD;
  } else {
    idx = bid - (T_TOK / 8 + 2048); in = W2; ow = W2T; R = FFD; C = HD;
  }
  const int cpt = C >> 6;   // 64-col tiles per row
  const int rpt = R >> 7;   // 128-row tiles per col
  const int cx = idx % cpt;
  const int ry = (idx / cpt) % rpt;
  const int z  = idx / (cpt * rpt);
  const int r0 = ry << 7, c0 = cx << 6;

  // phase 1: lane owns a 4x4 fp32 block (rows r0+rg*4.., cols c0+cg*4..)
  const int rg = tid >> 4;   // 0..31 (k-group)
  const int cg = tid & 15;   // 0..15 (n-group)
  {
    const float* ip = in + ((size_t)z * R + r0 + rg * 4) * C + c0 + cg * 4;
    float4 v0 = *(const float4*)(ip);
    float4 v1 = *(const float4*)(ip + C);
    float4 v2 = *(const float4*)(ip + 2 * (size_t)C);
    float4 v3 = *(const float4*)(ip + 3 * (size_t)C);
#pragma unroll
    for (int i = 0; i < 4; ++i) {
      const int n   = cg * 4 + i;
      const int c8  = rg ^ (2 * (n & 15));      // swizzled 8B-chunk index
      ushort4 u;
      u.x = f2bf((&v0.x)[i]); u.y = f2bf((&v1.x)[i]);
      u.z = f2bf((&v2.x)[i]); u.w = f2bf((&v3.x)[i]);
      *(ushort4*)&tt[n * 128 + c8 * 4] = u;
    }
  }
  __syncthreads();
  // phase 2: 16B/lane, 256B contiguous per 16-lane group (full 128-row column)
#pragma unroll
  for (int p = 0; p < 2; ++p) {
    const int n  = (tid >> 4) + p * 32;
    const int m  = tid & 15;                    // 16B k-chunk
    const int c8 = (2 * m) ^ (2 * (n & 15));    // swizzled (even -> 16B aligned)
    short8 val = *(const short8*)&tt[n * 128 + c8 * 4];
    *(short8*)(ow + ((size_t)z * C + c0 + n) * R + r0 + m * 8) = val;
  }
}

// ---------------- route: per-expert compaction via prefix scan (deterministic) ----
__global__ __launch_bounds__(256) void route_kernel(
    const int* __restrict__ top_i, const float2* __restrict__ top_w,
    int* __restrict__ counts, int* __restrict__ ids, float* __restrict__ wts)
{
  const int e   = blockIdx.x;
  const int tid = threadIdx.x;
  __shared__ int psum[256];

  const int t0 = tid * 16;
  unsigned int flags = 0;
  int cnt = 0;
#pragma unroll
  for (int j = 0; j < 16; ++j) {
    int ti = top_i[t0 + j];
    bool m = ((ti & 255) == e) || (((ti >> 8) & 255) == e);
    flags |= (m ? 1u : 0u) << j;
    cnt += m;
  }
  psum[tid] = cnt;
  __syncthreads();
  for (int off = 1; off < 256; off <<= 1) {
    int v = (tid >= off) ? psum[tid - off] : 0;
    __syncthreads();
    psum[tid] += v;
    __syncthreads();
  }
  int rank = psum[tid] - cnt;
#pragma unroll
  for (int j = 0; j < 16; ++j) {
    if (flags & (1u << j)) {
      int t = t0 + j;
      int ti = top_i[t];
      float2 w = top_w[t];
      ids[e * T_TOK + rank] = t;
      wts[e * T_TOK + rank] = ((ti & 255) == e) ? w.x : w.y;
      ++rank;
    }
  }
  if (tid == 255) counts[e] = psum[255];
}

// ---------------- grouped pair-GEMM: r13 structure VERBATIM ----------------------
// 128^2 tile, 4 waves, single-buffered 32KB LDS, 2 barriers/K-step, 4-5 blk/CU.
// Cross-block TLP is the latency-hiding mechanism (r8/r10/r12 all proved dbuf
// variants lose). e = bid&7 pins expert to XCD. XOR swizzle: 0 conflicts.
template<int KD, int ND, bool G1M, bool GATHER_A>
__global__ __launch_bounds__(256, 4) void pair_gemm128_kernel(
    const unsigned short* __restrict__ A,
    const unsigned short* __restrict__ BT,
    const float* __restrict__ bias,
    const int* __restrict__ counts, const int* __restrict__ ids,
    const float* __restrict__ wts,
    unsigned short* __restrict__ Hout, float* __restrict__ out)
{
  constexpr int CT = ND / 128;

  const int e    = blockIdx.x & 7;
  const int slot = blockIdx.x >> 3;
  int cnt = 0, base = 0;
#pragma unroll
  for (int k = 0; k < NE; ++k) {
    int c = counts[k];
    if (k < e)  base += (c + 255) & ~255;
    if (k == e) cnt = c;
  }
  const int ntiles = (cnt + 127) >> 7;
  if (slot >= ntiles * CT) return;
  const int rt   = slot % ntiles;   // fastest -> B tile hot in this XCD's L2
  const int ct   = slot / ntiles;
  const int row0 = base + rt * 128;

  __shared__ __align__(16) unsigned short As[128 * 64];
  __shared__ __align__(16) unsigned short Bs[128 * 64];

  const int tid  = threadIdx.x;
  const int w    = tid >> 6;
  const int lane = tid & 63;
  const int g    = lane >> 4;     // k-group 0..3
  const int rA   = lane & 15;     // row/col within fragment
  const int wr   = w >> 1;        // wave quadrant row 0..1
  const int wc   = w & 1;         // wave quadrant col 0..1
  const int sw   = rA & 7;        // read-side swizzle key
  const int srow = lane >> 3;                 // staging row in 8-row group
  const int lc8  = ((lane & 7) ^ srow) * 8;   // pre-swizzled source chunk

  const unsigned short* arow[4];
#pragma unroll
  for (int jj = 0; jj < 4; ++jj) {
    const int lrow = w * 32 + jj * 8 + srow;
    int src;
    if constexpr (GATHER_A) {
      int i = rt * 128 + lrow;
      src = ids[e * T_TOK + (i < cnt ? i : cnt - 1)];
    } else {
      src = row0 + lrow;
    }
    arow[jj] = A + (size_t)src * KD + lc8;
  }
  const unsigned short* Bb = BT + ((size_t)e * ND + (size_t)ct * 128) * KD + lc8;

  f32x4 acc[4][4];
#pragma unroll
  for (int mf = 0; mf < 4; ++mf)
#pragma unroll
    for (int nf = 0; nf < 4; ++nf)
      acc[mf][nf] = (f32x4){0.f, 0.f, 0.f, 0.f};

  for (int kc = 0; kc < KD; kc += 64) {
    __syncthreads();   // all waves done reading As/Bs
#pragma unroll
    for (int jj = 0; jj < 4; ++jj) {
      const int rg = w * 32 + jj * 8;
      gload_lds16(arow[jj] + kc, &As[rg * 64]);
      gload_lds16(Bb + (size_t)(rg + srow) * KD + kc, &Bs[rg * 64]);
    }
    __syncthreads();   // drain; 4-5 blk/CU cross-block TLP hides it (m97 mechanism)
#pragma unroll
    for (int ks = 0; ks < 2; ++ks) {
      const int pc = ((ks * 4 + g) ^ sw) << 3;
      short8 af[4], bf[4];
#pragma unroll
      for (int mf = 0; mf < 4; ++mf)
        af[mf] = *(const short8*)&As[(wr * 64 + mf * 16 + rA) * 64 + pc];
#pragma unroll
      for (int nf = 0; nf < 4; ++nf)
        bf[nf] = *(const short8*)&Bs[(wc * 64 + nf * 16 + rA) * 64 + pc];
#pragma unroll
      for (int mf = 0; mf < 4; ++mf)
#pragma unroll
        for (int nf = 0; nf < 4; ++nf)
          acc[mf][nf] = __builtin_amdgcn_mfma_f32_16x16x32_bf16(
              af[mf], bf[nf], acc[mf][nf], 0, 0, 0);
    }
  }

  // ---- epilogue ----
  float bv[4];
#pragma unroll
  for (int nf = 0; nf < 4; ++nf)
    bv[nf] = bias[e * ND + ct * 128 + wc * 64 + nf * 16 + rA];

  if constexpr (G1M) {
#pragma unroll
    for (int mf = 0; mf < 4; ++mf)
#pragma unroll
      for (int r = 0; r < 4; ++r) {
        const int row = row0 + wr * 64 + mf * 16 + g * 4 + r;
        unsigned short* hrow = Hout + (size_t)row * FFD + ct * 128 + wc * 64 + rA;
#pragma unroll
        for (int nf = 0; nf < 4; ++nf)
          hrow[nf * 16] = f2bf(fmaxf(acc[mf][nf][r] + bv[nf], 0.f));
      }
  } else {
#pragma unroll
    for (int mf = 0; mf < 4; ++mf)
#pragma unroll
      for (int r = 0; r < 4; ++r) {
        const int i = rt * 128 + wr * 64 + mf * 16 + g * 4 + r;
        if (i >= cnt) continue;
        const int tok = ids[e * T_TOK + i];
        const float wt = wts[e * T_TOK + i];
        float* orow = out + (size_t)tok * HD + ct * 128 + wc * 64 + rA;
#pragma unroll
        for (int nf = 0; nf < 4; ++nf)
          atomicAdd(&orow[nf * 16], wt * (acc[mf][nf][r] + bv[nf]));
      }
  }
}

extern "C" void kernel_launch(void* const* d_in, const int* in_sizes, int n_in,
                              void* d_out, int out_size, void* d_ws, size_t ws_size,
                              hipStream_t stream) {
  const float* x  = (const float*)d_in[0];
  const float* Wg = (const float*)d_in[1];
  const float* bg = (const float*)d_in[2];
  const float* W1 = (const float*)d_in[3];
  const float* b1 = (const float*)d_in[4];
  const float* W2 = (const float*)d_in[5];
  const float* b2 = (const float*)d_in[6];
  float* out = (float*)d_out;

  // ws: [counts 512B][top_i 16K][top_w 32K][ids 128K][wts 128K]
  //     [xbf 8MB][W1T 32MB][W2T 32MB][H 40MB]  ~= 112.8 MB (<= 118.3 proven)
  const size_t OFF_TOPI = 512;
  const size_t OFF_TOPW = OFF_TOPI + (size_t)T_TOK * 4;
  const size_t OFF_IDS  = OFF_TOPW + (size_t)T_TOK * 8;
  const size_t OFF_WTS  = OFF_IDS + (size_t)T_TOK * NE * 4;
  const size_t OFF_XBF  = OFF_WTS + (size_t)T_TOK * NE * 4;
  const size_t OFF_W1T  = OFF_XBF + (size_t)T_TOK * HD * 2;
  const size_t OFF_W2T  = OFF_W1T + (size_t)NE * HD * FFD * 2;
  const size_t OFF_H    = OFF_W2T + (size_t)NE * HD * FFD * 2;
  const size_t REQ      = OFF_H + (size_t)10240 * FFD * 2;

  if (ws_size < REQ) return;

  int*            counts = (int*)d_ws;
  int*            top_i  = (int*)((char*)d_ws + OFF_TOPI);
  float2*         top_w  = (float2*)((char*)d_ws + OFF_TOPW);
  int*            ids    = (int*)((char*)d_ws + OFF_IDS);
  float*          wts    = (float*)((char*)d_ws + OFF_WTS);
  unsigned short* xbf    = (unsigned short*)((char*)d_ws + OFF_XBF);
  unsigned short* W1T    = (unsigned short*)((char*)d_ws + OFF_W1T);
  unsigned short* W2T    = (unsigned short*)((char*)d_ws + OFF_W2T);
  unsigned short* H      = (unsigned short*)((char*)d_ws + OFF_H);

  // fused prep: gate (512) + W1T (2048) + W2T (2048), 512 threads each
  prep_kernel<<<T_TOK / 8 + 2 * 2048, 512, 0, stream>>>(
      x, Wg, bg, W1, W2, top_i, top_w, xbf, W1T, W2T, out);
  route_kernel<<<NE, 256, 0, stream>>>(top_i, top_w, counts, ids, wts);

  // G1: over-provisioned (worst case ntiles=32, CT=16), dead blocks exit instantly
  pair_gemm128_kernel<HD, FFD, true, true>
      <<<NE * 512, 256, 0, stream>>>(xbf, W1T, b1, counts, ids, wts, H, nullptr);
  // G2: worst case ntiles=32, CT=8
  pair_gemm128_kernel<FFD, HD, false, false>
      <<<NE * 256, 256, 0, stream>>>(H, W2T, b2, counts, ids, wts, nullptr, out);
}

// Round 15
// 167.372 us; speedup vs baseline: 1.4080x; 1.0149x over previous
//
#include <hip/hip_runtime.h>
#include <hip/hip_bf16.h>

#define T_TOK 4096
#define HD    1024
#define FFD   2048
#define NE    8

typedef __attribute__((ext_vector_type(8))) short short8;
typedef __attribute__((ext_vector_type(4))) float f32x4;

__device__ __forceinline__ unsigned short f2bf(float f) {
  __hip_bfloat16 h = __float2bfloat16(f);
  return __builtin_bit_cast(unsigned short, h);
}

__device__ __forceinline__ void gload_lds16(const unsigned short* g, unsigned short* l) {
  __builtin_amdgcn_global_load_lds(
      (const __attribute__((address_space(1))) unsigned int*)g,
      (__attribute__((address_space(3))) unsigned int*)l, 16, 0, 0);
}

// ---------------- conflict-free 128(k) x 64(n) transpose tile ---------------------
// in [E][R][C] fp32 -> out [E][C][R] bf16.  256 threads, 16KB LDS tile.
// Lane owns 8 rows x 4 cols: 8 x float4 coalesced loads (4 x 256B segs/instr).
// LDS: [64 n][128 k] ushort; 16B chunk c16 = rg ^ ((cg&3)<<2).
//   Phase-1 banks (wave: rg 0..3, cg 0..15): c16 mod 8 = rg^(4*(cg&1)) -> 8 quads
//   uniform, 8 words/bank = b128 floor, ZERO extra conflict (r14 had 8-way).
//   Phase-2: c16 = m ^ key(n); m spans 0..15 -> conflict-free for any key.
// Stores: 16 lanes x 16B = 256B contiguous per column.
__device__ __forceinline__ void transpose_tile(
    const float* __restrict__ in, unsigned short* __restrict__ ow,
    int R, int C, int idx, unsigned short* tt, int tid)
{
  const int cpt = C >> 6, rpt = R >> 7;
  const int cx = idx % cpt;
  const int ry = (idx / cpt) % rpt;
  const int z  = idx / (cpt * rpt);
  const int r0 = ry << 7, c0 = cx << 6;

  const int rg  = tid >> 4;              // 0..15: rows rg*8 .. rg*8+7
  const int cg  = tid & 15;              // cols cg*4 .. cg*4+3
  const int c16 = rg ^ ((cg & 3) << 2);  // swizzled 16B chunk (write side)

  const float* ip = in + ((size_t)z * R + r0 + rg * 8) * C + c0 + cg * 4;
  float4 v[8];
#pragma unroll
  for (int r = 0; r < 8; ++r)
    v[r] = *(const float4*)(ip + (size_t)r * C);
#pragma unroll
  for (int i = 0; i < 4; ++i) {
    const int n = cg * 4 + i;
    short8 u;
#pragma unroll
    for (int r = 0; r < 8; ++r) u[r] = (short)f2bf((&v[r].x)[i]);
    *(short8*)&tt[n * 128 + c16 * 8] = u;
  }
  __syncthreads();
#pragma unroll
  for (int p = 0; p < 4; ++p) {
    const int n  = (tid >> 4) + p * 16;
    const int m  = tid & 15;
    const int rc = m ^ (((n >> 2) & 3) << 2);   // same key as write side
    short8 val = *(const short8*)&tt[n * 128 + rc * 8];
    *(short8*)(ow + ((size_t)z * C + c0 + n) * R + r0 + m * 8) = val;
  }
}

// ---------------- fused prep: gate (+zero out, +x->bf16) || W1^T ------------------
// Sections: [0,1024) gate (4 tok/block), [1024,3072) W1T transpose.
__global__ __launch_bounds__(256) void prep_kernel(
    const float* __restrict__ x, const float* __restrict__ Wg,
    const float* __restrict__ bg, const float* __restrict__ W1,
    int* __restrict__ top_i, float2* __restrict__ top_w,
    unsigned short* __restrict__ xbf, unsigned short* __restrict__ W1T,
    float* __restrict__ out)
{
  __shared__ unsigned short tt[64 * 128];   // 16 KB -> 8 blocks/CU
  const int bid = blockIdx.x;
  const int tid = threadIdx.x;

  if (bid >= T_TOK / 4) {
    transpose_tile(W1, W1T, HD, FFD, bid - T_TOK / 4, tt, tid);
    return;
  }

  // ---- gate section ----
  {
    size_t b = ((size_t)bid * 256 + tid) * 16;
    float4 z = make_float4(0.f, 0.f, 0.f, 0.f);
#pragma unroll
    for (int q = 0; q < 4; ++q) *(float4*)(out + b + q * 4) = z;
  }
  const int wave = tid >> 6;
  const int lane = tid & 63;
  const int t = bid * 4 + wave;

  float acc[NE];
#pragma unroll
  for (int e = 0; e < NE; ++e) acc[e] = 0.f;

  const float* xr = x + (size_t)t * HD;
  unsigned short* xo = xbf + (size_t)t * HD;
#pragma unroll
  for (int it = 0; it < 4; ++it) {
    const int h0 = lane * 4 + it * 256;
    float4 xv = *(const float4*)(xr + h0);
#pragma unroll
    for (int j = 0; j < 4; ++j) {
      float xs = (&xv.x)[j];
      float4 a = *(const float4*)(Wg + (size_t)(h0 + j) * NE);
      float4 b = *(const float4*)(Wg + (size_t)(h0 + j) * NE + 4);
      acc[0] = fmaf(xs, a.x, acc[0]); acc[1] = fmaf(xs, a.y, acc[1]);
      acc[2] = fmaf(xs, a.z, acc[2]); acc[3] = fmaf(xs, a.w, acc[3]);
      acc[4] = fmaf(xs, b.x, acc[4]); acc[5] = fmaf(xs, b.y, acc[5]);
      acc[6] = fmaf(xs, b.z, acc[6]); acc[7] = fmaf(xs, b.w, acc[7]);
    }
    ushort4 u;
    u.x = f2bf(xv.x); u.y = f2bf(xv.y); u.z = f2bf(xv.z); u.w = f2bf(xv.w);
    *(ushort4*)(xo + h0) = u;
  }
#pragma unroll
  for (int off = 32; off > 0; off >>= 1) {
#pragma unroll
    for (int e = 0; e < NE; ++e) acc[e] += __shfl_xor(acc[e], off);
  }
  if (lane == 0) {
    float lg[NE];
#pragma unroll
    for (int e = 0; e < NE; ++e) lg[e] = acc[e] + bg[e];
    int i1 = 0;
#pragma unroll
    for (int e = 1; e < NE; ++e) if (lg[e] > lg[i1]) i1 = e;
    int i2 = (i1 == 0) ? 1 : 0;
#pragma unroll
    for (int e = 0; e < NE; ++e) if (e != i1 && lg[e] > lg[i2]) i2 = e;
    float p2 = expf(lg[i2] - lg[i1]);
    float s  = 1.f + p2;
    top_i[t] = i1 | (i2 << 8);
    top_w[t] = make_float2(1.f / s, p2 / s);
  }
}

// ---------------- route: per-expert compaction via prefix scan (deterministic) ----
__global__ __launch_bounds__(256) void route_kernel(
    const int* __restrict__ top_i, const float2* __restrict__ top_w,
    int* __restrict__ counts, int* __restrict__ ids, float* __restrict__ wts)
{
  const int e   = blockIdx.x;
  const int tid = threadIdx.x;
  __shared__ int psum[256];

  const int t0 = tid * 16;
  unsigned int flags = 0;
  int cnt = 0;
#pragma unroll
  for (int j = 0; j < 16; ++j) {
    int ti = top_i[t0 + j];
    bool m = ((ti & 255) == e) || (((ti >> 8) & 255) == e);
    flags |= (m ? 1u : 0u) << j;
    cnt += m;
  }
  psum[tid] = cnt;
  __syncthreads();
  for (int off = 1; off < 256; off <<= 1) {
    int v = (tid >= off) ? psum[tid - off] : 0;
    __syncthreads();
    psum[tid] += v;
    __syncthreads();
  }
  int rank = psum[tid] - cnt;
#pragma unroll
  for (int j = 0; j < 16; ++j) {
    if (flags & (1u << j)) {
      int t = t0 + j;
      int ti = top_i[t];
      float2 w = top_w[t];
      ids[e * T_TOK + rank] = t;
      wts[e * T_TOK + rank] = ((ti & 255) == e) ? w.x : w.y;
      ++rank;
    }
  }
  if (tid == 255) counts[e] = psum[255];
}

// ---------------- grouped pair-GEMM: r13 structure + optional fused transpose -----
// 128^2 tile, 4 waves, single-buffered 32KB LDS, 2 barriers/K-step, 4-5 blk/CU.
// Cross-block TLP hides latency (r8/r10/r12 proved dbuf variants lose).
// e = bid&7 pins expert to XCD. XOR swizzle: 0 conflicts (r5-r14).
// FUSET: blocks with bid >= tbase transpose Wsrc->Wdst instead (BW-bound work
// overlapping the compute-bound GEMM; 16KB tile aliases As).
template<int KD, int ND, bool G1M, bool GATHER_A, bool FUSET>
__global__ __launch_bounds__(256, 4) void pair_gemm128_kernel(
    const unsigned short* __restrict__ A,
    const unsigned short* __restrict__ BT,
    const float* __restrict__ bias,
    const int* __restrict__ counts, const int* __restrict__ ids,
    const float* __restrict__ wts,
    unsigned short* __restrict__ Hout, float* __restrict__ out,
    const float* __restrict__ Wsrc, unsigned short* __restrict__ Wdst,
    int TR, int TC, int tbase)
{
  constexpr int CT = ND / 128;

  __shared__ __align__(16) unsigned short As[128 * 64];
  __shared__ __align__(16) unsigned short Bs[128 * 64];

  const int tid = threadIdx.x;

  if constexpr (FUSET) {
    if ((int)blockIdx.x >= tbase) {
      transpose_tile(Wsrc, Wdst, TR, TC, blockIdx.x - tbase, As, tid);
      return;
    }
  }

  const int e    = blockIdx.x & 7;
  const int slot = blockIdx.x >> 3;
  int cnt = 0, base = 0;
#pragma unroll
  for (int k = 0; k < NE; ++k) {
    int c = counts[k];
    if (k < e)  base += (c + 255) & ~255;
    if (k == e) cnt = c;
  }
  const int ntiles = (cnt + 127) >> 7;
  if (slot >= ntiles * CT) return;
  const int rt   = slot % ntiles;   // fastest -> B tile hot in this XCD's L2
  const int ct   = slot / ntiles;
  const int row0 = base + rt * 128;

  const int w    = tid >> 6;
  const int lane = tid & 63;
  const int g    = lane >> 4;     // k-group 0..3
  const int rA   = lane & 15;     // row/col within fragment
  const int wr   = w >> 1;        // wave quadrant row 0..1
  const int wc   = w & 1;         // wave quadrant col 0..1
  const int sw   = rA & 7;        // read-side swizzle key
  const int srow = lane >> 3;                 // staging row in 8-row group
  const int lc8  = ((lane & 7) ^ srow) * 8;   // pre-swizzled source chunk

  const unsigned short* arow[4];
#pragma unroll
  for (int jj = 0; jj < 4; ++jj) {
    const int lrow = w * 32 + jj * 8 + srow;
    int src;
    if constexpr (GATHER_A) {
      int i = rt * 128 + lrow;
      src = ids[e * T_TOK + (i < cnt ? i : cnt - 1)];
    } else {
      src = row0 + lrow;
    }
    arow[jj] = A + (size_t)src * KD + lc8;
  }
  const unsigned short* Bb = BT + ((size_t)e * ND + (size_t)ct * 128) * KD + lc8;

  f32x4 acc[4][4];
#pragma unroll
  for (int mf = 0; mf < 4; ++mf)
#pragma unroll
    for (int nf = 0; nf < 4; ++nf)
      acc[mf][nf] = (f32x4){0.f, 0.f, 0.f, 0.f};

  for (int kc = 0; kc < KD; kc += 64) {
    __syncthreads();   // all waves done reading As/Bs
#pragma unroll
    for (int jj = 0; jj < 4; ++jj) {
      const int rg = w * 32 + jj * 8;
      gload_lds16(arow[jj] + kc, &As[rg * 64]);
      gload_lds16(Bb + (size_t)(rg + srow) * KD + kc, &Bs[rg * 64]);
    }
    __syncthreads();   // drain; 4-5 blk/CU cross-block TLP hides it (m97 mechanism)
#pragma unroll
    for (int ks = 0; ks < 2; ++ks) {
      const int pc = ((ks * 4 + g) ^ sw) << 3;
      short8 af[4], bf[4];
#pragma unroll
      for (int mf = 0; mf < 4; ++mf)
        af[mf] = *(const short8*)&As[(wr * 64 + mf * 16 + rA) * 64 + pc];
#pragma unroll
      for (int nf = 0; nf < 4; ++nf)
        bf[nf] = *(const short8*)&Bs[(wc * 64 + nf * 16 + rA) * 64 + pc];
#pragma unroll
      for (int mf = 0; mf < 4; ++mf)
#pragma unroll
        for (int nf = 0; nf < 4; ++nf)
          acc[mf][nf] = __builtin_amdgcn_mfma_f32_16x16x32_bf16(
              af[mf], bf[nf], acc[mf][nf], 0, 0, 0);
    }
  }

  // ---- epilogue ----
  float bv[4];
#pragma unroll
  for (int nf = 0; nf < 4; ++nf)
    bv[nf] = bias[e * ND + ct * 128 + wc * 64 + nf * 16 + rA];

  if constexpr (G1M) {
#pragma unroll
    for (int mf = 0; mf < 4; ++mf)
#pragma unroll
      for (int r = 0; r < 4; ++r) {
        const int row = row0 + wr * 64 + mf * 16 + g * 4 + r;
        unsigned short* hrow = Hout + (size_t)row * FFD + ct * 128 + wc * 64 + rA;
#pragma unroll
        for (int nf = 0; nf < 4; ++nf)
          hrow[nf * 16] = f2bf(fmaxf(acc[mf][nf][r] + bv[nf], 0.f));
      }
  } else {
#pragma unroll
    for (int mf = 0; mf < 4; ++mf)
#pragma unroll
      for (int r = 0; r < 4; ++r) {
        const int i = rt * 128 + wr * 64 + mf * 16 + g * 4 + r;
        if (i >= cnt) continue;
        const int tok = ids[e * T_TOK + i];
        const float wt = wts[e * T_TOK + i];
        float* orow = out + (size_t)tok * HD + ct * 128 + wc * 64 + rA;
#pragma unroll
        for (int nf = 0; nf < 4; ++nf)
          atomicAdd(&orow[nf * 16], wt * (acc[mf][nf][r] + bv[nf]));
      }
  }
}

extern "C" void kernel_launch(void* const* d_in, const int* in_sizes, int n_in,
                              void* d_out, int out_size, void* d_ws, size_t ws_size,
                              hipStream_t stream) {
  const float* x  = (const float*)d_in[0];
  const float* Wg = (const float*)d_in[1];
  const float* bg = (const float*)d_in[2];
  const float* W1 = (const float*)d_in[3];
  const float* b1 = (const float*)d_in[4];
  const float* W2 = (const float*)d_in[5];
  const float* b2 = (const float*)d_in[6];
  float* out = (float*)d_out;

  // ws: [counts 512B][top_i 16K][top_w 32K][ids 128K][wts 128K]
  //     [xbf 8MB][W1T 32MB][W2T 32MB][H 40MB]  ~= 112.8 MB (<= 118.3 proven)
  const size_t OFF_TOPI = 512;
  const size_t OFF_TOPW = OFF_TOPI + (size_t)T_TOK * 4;
  const size_t OFF_IDS  = OFF_TOPW + (size_t)T_TOK * 8;
  const size_t OFF_WTS  = OFF_IDS + (size_t)T_TOK * NE * 4;
  const size_t OFF_XBF  = OFF_WTS + (size_t)T_TOK * NE * 4;
  const size_t OFF_W1T  = OFF_XBF + (size_t)T_TOK * HD * 2;
  const size_t OFF_W2T  = OFF_W1T + (size_t)NE * HD * FFD * 2;
  const size_t OFF_H    = OFF_W2T + (size_t)NE * HD * FFD * 2;
  const size_t REQ      = OFF_H + (size_t)10240 * FFD * 2;

  if (ws_size < REQ) return;

  int*            counts = (int*)d_ws;
  int*            top_i  = (int*)((char*)d_ws + OFF_TOPI);
  float2*         top_w  = (float2*)((char*)d_ws + OFF_TOPW);
  int*            ids    = (int*)((char*)d_ws + OFF_IDS);
  float*          wts    = (float*)((char*)d_ws + OFF_WTS);
  unsigned short* xbf    = (unsigned short*)((char*)d_ws + OFF_XBF);
  unsigned short* W1T    = (unsigned short*)((char*)d_ws + OFF_W1T);
  unsigned short* W2T    = (unsigned short*)((char*)d_ws + OFF_W2T);
  unsigned short* H      = (unsigned short*)((char*)d_ws + OFF_H);

  // prep: gate (1024 blocks) + W1T transpose (2048 blocks, conflict-free tiles)
  prep_kernel<<<T_TOK / 4 + 2048, 256, 0, stream>>>(
      x, Wg, bg, W1, top_i, top_w, xbf, W1T, out);
  route_kernel<<<NE, 256, 0, stream>>>(top_i, top_w, counts, ids, wts);

  // G1 (over-provisioned GEMM blocks) + fused W2T transpose (2048 tail blocks):
  // BW-bound transpose overlaps compute-bound GEMM; W2T ready before G2 (stream order)
  const int tbase = NE * 512;
  pair_gemm128_kernel<HD, FFD, true, true, true>
      <<<tbase + 2048, 256, 0, stream>>>(xbf, W1T, b1, counts, ids, wts, H, nullptr,
                                         W2, W2T, FFD, HD, tbase);
  // G2
  pair_gemm128_kernel<FFD, HD, false, false, false>
      <<<NE * 256, 256, 0, stream>>>(H, W2T, b2, counts, ids, wts, nullptr, out,
                                     nullptr, nullptr, 0, 0, 0);
}